// Round 8
// baseline (999.839 us; speedup 1.0000x reference)
//
#include <hip/hip_runtime.h>
#include <hip/hip_bf16.h>

// Problem constants
#define BB 32
#define TT 1500
#define TP 1536      // T padded to 12*128 for GEMM tiles
#define EE 512
#define HH 4
#define AA 512
#define NN 2048      // H*A
#define CC 10
#define KCONV 201
#define KAUG 576     // 512 enc + 40 conv + 24 zero pad (18 k-steps of 32)

typedef __attribute__((ext_vector_type(8))) __bf16 bf16x8;
typedef __attribute__((ext_vector_type(4))) float f32x4;

union U16 { uint4 u; bf16x8 v; };

// ---------- helpers ----------
__device__ __forceinline__ unsigned short f2bf(float x) {
    unsigned int u = __float_as_uint(x);
    u = (u + 0x7fffu + ((u >> 16) & 1u)) >> 16;   // RNE, inputs always finite
    return (unsigned short)u;
}
__device__ __forceinline__ float bf2f(unsigned short u) {
    return __uint_as_float(((unsigned int)u) << 16);
}
// tanh(x) = 1 - 2/(e^{2x}+1); saturates correctly at +-inf; abs err ~1e-6.
__device__ __forceinline__ float tanh_fast(float x) {
    float e = __expf(x * 2.0f);
    return fmaf(-2.0f, __builtin_amdgcn_rcpf(e + 1.0f), 1.0f);
}
// packed f32x2 -> bf16x2 (RNE)
__device__ __forceinline__ unsigned int pkbf(float x, float y) {
    float2 f{x, y};
    __hip_bfloat162 h2 = __float22bfloat162_rn(f);
    return *reinterpret_cast<unsigned int*>(&h2);
}
// split pair into packed hi bf16x2 and packed lo (residual) bf16x2
__device__ __forceinline__ void split2(float x, float y, unsigned int& h, unsigned int& l) {
    unsigned short hx = f2bf(x), hy = f2bf(y);
    h = ((unsigned int)hy << 16) | hx;
    l = pkbf(x - bf2f(hx), y - bf2f(hy));
}

// Fused prep kernel: block-range dispatch of 4 phases.
#define PREP_ZERO0  0
#define PREP_DEC0   1024
#define PREP_CONV0  2048
#define PREP_WT0    9728
#define PREP_TOTAL  10016

__global__ __launch_bounds__(256) void k_prep(
    const float* __restrict__ dec_out, const float* __restrict__ aw_step,
    const float* __restrict__ w_enc, const float* __restrict__ b_enc,
    const float* __restrict__ w_dec, const float* __restrict__ w_conv,
    const float* __restrict__ conv_k,
    unsigned short* __restrict__ Whi, unsigned short* __restrict__ Wlo,
    unsigned short* __restrict__ Chi, unsigned short* __restrict__ Clo,
    float* __restrict__ dec_a, float* __restrict__ zbase) {
    __shared__ float sh[64 * 65];   // wt transpose tile; aliased by dec/conv scratch
    const int bid = blockIdx.x;
    const int tid = threadIdx.x;

    if (bid < PREP_DEC0) {
        // ---- zero: energy + ctx_h (contiguous) ----
        zbase[bid * 256 + tid] = 0.f;
    } else if (bid < PREP_CONV0) {
        // ---- dec: dec_a[b][n] = b_enc[n] + sum_d dec[b][d]*w_dec[h][d][a] ----
        const int rb = bid - PREP_DEC0;
        const int b  = rb >> 5;
        const int n0 = (rb & 31) * 64;
        const int n  = n0 + (tid & 63);
        const int dg = tid >> 6;                   // 0..3, 128 d each
        const int h  = n >> 9, a = n & 511;
        const float* dp = dec_out + (size_t)b * 512 + dg * 128;
        const float* wp = w_dec + ((size_t)h * 512 + dg * 128) * 512 + a;
        float acc = 0.f;
#pragma unroll 8
        for (int d = 0; d < 128; ++d) acc += dp[d] * wp[(size_t)d * 512];
        sh[tid] = acc;
        __syncthreads();
        if (tid < 64) {
            float tot = sh[tid] + sh[tid + 64] + sh[tid + 128] + sh[tid + 192];
            dec_a[(size_t)b * NN + n0 + tid] = b_enc[n0 + tid] + tot;
        }
    } else if (bid < PREP_WT0) {
        // ---- conv: grouped 1D conv over aw_step -> Chi/Clo[b][t][hc] ----
        int r = bid - PREP_CONV0;                  // 7680 = 6*40*32
        const int tch = r % 6;
        const int hc  = (r / 6) % 40;
        const int b   = r / 240;
        const int h   = hc / 10;
        const int t0  = tch * 256;
        float* sAw = sh;
        for (int i = tid; i < 456; i += 256) {
            int ts = t0 - 100 + i;
            sAw[i] = (ts >= 0 && ts < TT) ? aw_step[((size_t)b * TT + ts) * HH + h] : 0.f;
        }
        __syncthreads();
        int t = t0 + tid;
        if (t < TT) {
            const float* ck = conv_k + (size_t)hc * KCONV;   // uniform index -> s_load
            float acc = 0.f;
#pragma unroll 4
            for (int k = 0; k < KCONV; ++k) acc += sAw[tid + k] * ck[k];
            size_t o = ((size_t)b * TP + t) * 64 + hc;
            unsigned short hi = f2bf(acc);
            Chi[o] = hi; Clo[o] = f2bf(acc - bf2f(hi));
        }
    } else {
        // ---- wt: W planes [N=2048][KAUG], hi/lo; coalesced via LDS transpose ----
        int r = bid - PREP_WT0;                    // 0..287 = 4h * 8a * 9k
        const int h  = r / 72;
        const int rr = r % 72;
        const int at = rr / 9;
        const int kt = rr % 9;
        const int a0 = at * 64;
        if (kt < 8) {
            const int k0 = kt * 64;
#pragma unroll
            for (int it = 0; it < 16; ++it) {
                int kk = it * 4 + (tid >> 6);
                int aa = tid & 63;
                sh[kk * 65 + aa] = w_enc[((size_t)h * 512 + k0 + kk) * 512 + a0 + aa];
            }
            __syncthreads();
#pragma unroll
            for (int it = 0; it < 16; ++it) {
                int nl = it * 4 + (tid >> 6);
                int kk = tid & 63;
                float val = sh[kk * 65 + nl];
                size_t o = ((size_t)h * 512 + a0 + nl) * KAUG + k0 + kk;
                unsigned short hi = f2bf(val);
                Whi[o] = hi; Wlo[o] = f2bf(val - bf2f(hi));
            }
        } else {
            // k in [512,576): conv cols (block-diagonal per head) + zero pad
#pragma unroll
            for (int it = 0; it < 16; ++it) {
                int nl = it * 4 + (tid >> 6);
                int j  = tid & 63;
                float val = 0.f;
                if (j < 40 && (j / 10) == h)
                    val = w_conv[((size_t)h * 10 + (j % 10)) * 512 + a0 + nl];
                size_t o = ((size_t)h * 512 + a0 + nl) * KAUG + 512 + j;
                unsigned short hi = f2bf(val);
                Whi[o] = hi; Wlo[o] = f2bf(val - bf2f(hi));
            }
        }
    }
}

// ---------- shared epilogue: x = acc + dec_a; energy += tanh(x)*v, reduce over A ----------
__device__ __forceinline__ void gemm_epilogue(
    f32x4 (&acc)[4][4], const float* __restrict__ dec_a, const float* __restrict__ vvec,
    float* __restrict__ energy, int b, int m0, int n0, int wm, int wn, int lane) {
    const int h = n0 >> 9;               // 128-wide tile lies inside one head
    const int kg = lane >> 4;
    float dv[4], vv[4];
#pragma unroll
    for (int j = 0; j < 4; j++) {
        int ng = n0 + wn * 64 + j * 16 + (lane & 15);
        dv[j] = dec_a[(size_t)b * NN + ng];
        vv[j] = vvec[ng];
    }
#pragma unroll
    for (int i = 0; i < 4; i++) {
        float part[4] = {0.f, 0.f, 0.f, 0.f};
#pragma unroll
        for (int j = 0; j < 4; j++)
#pragma unroll
            for (int r = 0; r < 4; r++)
                part[r] += tanh_fast(acc[i][j][r] + dv[j]) * vv[j];
#pragma unroll
        for (int r = 0; r < 4; r++) {
            float s = part[r];
            s += __shfl_xor(s, 1, 64);
            s += __shfl_xor(s, 2, 64);
            s += __shfl_xor(s, 4, 64);
            s += __shfl_xor(s, 8, 64);
            if ((lane & 15) == 0) {
                int t = m0 + wm * 64 + i * 16 + kg * 4 + r;
                if (t < TT)
                    atomicAdd(&energy[((size_t)b * HH + h) * TP + t], s);
            }
        }
    }
}

// ---------- k_gemm_v: barrier-free 1-product GEMM, fully-valid tiles ----------
// No LDS, no __syncthreads in the K-loop: each lane loads its MFMA fragments
// DIRECTLY from global (A: 2xfloat4 from enc rows -> in-register bf16 pack;
// B: one dwordx4 from the [N][K] W-plane). Latency hidden by wave-ILP + occupancy
// (LDS=0), not by barriers -- attacks r3..r7's structural barrier-chain stall.
__global__ __launch_bounds__(256) void k_gemm_v(
    const float* __restrict__ enc, const unsigned short* __restrict__ Chi,
    const unsigned short* __restrict__ Whi,
    const float* __restrict__ dec_a, const float* __restrict__ vvec,
    const int* __restrict__ xl, float* __restrict__ energy) {
    const int ntile = blockIdx.x, mtile = blockIdx.y, b = blockIdx.z;
    const int m0 = mtile * 128, n0 = ntile * 128;
    if (m0 + 128 > xl[b]) return;                 // padded tile -> k_gemm_p
    const int tid = threadIdx.x;
    const int lane = tid & 63, wave = tid >> 6;
    const int wm = wave >> 1, wn = wave & 1;
    const int ar = wm * 64, br = wn * 64;
    const int mrow = lane & 15;
    const int kq = (lane >> 4) * 8;

    f32x4 acc[4][4];
#pragma unroll
    for (int i = 0; i < 4; i++)
#pragma unroll
        for (int j = 0; j < 4; j++) acc[i][j] = (f32x4){0.f, 0.f, 0.f, 0.f};

    const float* ap[4];
    const unsigned short* bp[4];
#pragma unroll
    for (int i = 0; i < 4; i++) {
        ap[i] = enc + ((size_t)b * TT + m0 + ar + i * 16 + mrow) * 512 + kq;
        bp[i] = Whi + ((size_t)(n0 + br + i * 16 + mrow)) * KAUG + kq;
    }

#pragma unroll 2
    for (int ks = 0; ks < 16; ++ks) {
        const int k0 = ks * 32;
        U16 av[4], bv[4];
#pragma unroll
        for (int i = 0; i < 4; i++) {
            float4 f0 = *(const float4*)(ap[i] + k0);
            float4 f1 = *(const float4*)(ap[i] + k0 + 4);
            av[i].u.x = pkbf(f0.x, f0.y); av[i].u.y = pkbf(f0.z, f0.w);
            av[i].u.z = pkbf(f1.x, f1.y); av[i].u.w = pkbf(f1.z, f1.w);
            bv[i].u = *(const uint4*)(bp[i] + k0);
        }
#pragma unroll
        for (int i = 0; i < 4; i++)
#pragma unroll
            for (int j = 0; j < 4; j++)
                acc[i][j] = __builtin_amdgcn_mfma_f32_16x16x32_bf16(av[i].v, bv[j].v, acc[i][j], 0, 0, 0);
    }
    // conv K-steps (k 512..576) from Chi plane [B][TP][64]
#pragma unroll
    for (int ks = 16; ks < 18; ++ks) {
        U16 av[4], bv[4];
#pragma unroll
        for (int i = 0; i < 4; i++) {
            av[i].u = *(const uint4*)(Chi + ((size_t)b * TP + m0 + ar + i * 16 + mrow) * 64 + (ks - 16) * 32 + kq);
            bv[i].u = *(const uint4*)(bp[i] + ks * 32);
        }
#pragma unroll
        for (int i = 0; i < 4; i++)
#pragma unroll
            for (int j = 0; j < 4; j++)
                acc[i][j] = __builtin_amdgcn_mfma_f32_16x16x32_bf16(av[i].v, bv[j].v, acc[i][j], 0, 0, 0);
    }

    gemm_epilogue(acc, dec_a, vvec, energy, b, m0, n0, wm, wn, lane);
}

// ---------- k_gemm_p: barrier-free 3-product split-bf16 GEMM, padded tiles ----------
__global__ __launch_bounds__(256) void k_gemm_p(
    const float* __restrict__ enc,
    const unsigned short* __restrict__ Chi, const unsigned short* __restrict__ Clo,
    const unsigned short* __restrict__ Whi, const unsigned short* __restrict__ Wlo,
    const float* __restrict__ dec_a, const float* __restrict__ vvec,
    const int* __restrict__ xl, float* __restrict__ energy) {
    const int ntile = blockIdx.x, mtile = blockIdx.y, b = blockIdx.z;
    const int m0 = mtile * 128, n0 = ntile * 128;
    const int xlen = xl[b];
    if (m0 + 128 <= xlen) return;                 // valid tile -> k_gemm_v
    const int tid = threadIdx.x;
    const int lane = tid & 63, wave = tid >> 6;
    const int wm = wave >> 1, wn = wave & 1;
    const int ar = wm * 64, br = wn * 64;
    const int mrow = lane & 15;
    const int kq = (lane >> 4) * 8;

    f32x4 acc[4][4];
#pragma unroll
    for (int i = 0; i < 4; i++)
#pragma unroll
        for (int j = 0; j < 4; j++) acc[i][j] = (f32x4){0.f, 0.f, 0.f, 0.f};

    // wave-uniform: row-group i needs lo-correction only if it has rows >= xlen
    bool corr[4];
#pragma unroll
    for (int i = 0; i < 4; i++) corr[i] = (m0 + ar + i * 16 + 16) > xlen;

    const float* ap[4];
    const unsigned short* bph[4];
    const unsigned short* bpl[4];
#pragma unroll
    for (int i = 0; i < 4; i++) {
        int t = m0 + ar + i * 16 + mrow;
        int tc = t < TT ? t : TT - 1;             // clamp: rows >=1500 feed discarded energy rows
        ap[i]  = enc + ((size_t)b * TT + tc) * 512 + kq;
        bph[i] = Whi + ((size_t)(n0 + br + i * 16 + mrow)) * KAUG + kq;
        bpl[i] = Wlo + ((size_t)(n0 + br + i * 16 + mrow)) * KAUG + kq;
    }

#pragma unroll 2
    for (int ks = 0; ks < 16; ++ks) {
        const int k0 = ks * 32;
        U16 ah[4], al[4], bh[4], bl[4];
#pragma unroll
        for (int i = 0; i < 4; i++) {
            float4 f0 = *(const float4*)(ap[i] + k0);
            float4 f1 = *(const float4*)(ap[i] + k0 + 4);
            split2(f0.x, f0.y, ah[i].u.x, al[i].u.x);
            split2(f0.z, f0.w, ah[i].u.y, al[i].u.y);
            split2(f1.x, f1.y, ah[i].u.z, al[i].u.z);
            split2(f1.z, f1.w, ah[i].u.w, al[i].u.w);
            bh[i].u = *(const uint4*)(bph[i] + k0);
            bl[i].u = *(const uint4*)(bpl[i] + k0);
        }
#pragma unroll
        for (int i = 0; i < 4; i++) {
#pragma unroll
            for (int j = 0; j < 4; j++)
                acc[i][j] = __builtin_amdgcn_mfma_f32_16x16x32_bf16(ah[i].v, bh[j].v, acc[i][j], 0, 0, 0);
            if (corr[i]) {
#pragma unroll
                for (int j = 0; j < 4; j++) {
                    acc[i][j] = __builtin_amdgcn_mfma_f32_16x16x32_bf16(ah[i].v, bl[j].v, acc[i][j], 0, 0, 0);
                    acc[i][j] = __builtin_amdgcn_mfma_f32_16x16x32_bf16(al[i].v, bh[j].v, acc[i][j], 0, 0, 0);
                }
            }
        }
    }
    // conv K-steps from Chi/Clo planes (rows >=1500 hold garbage (0xAA, finite) --
    // they only affect energy rows discarded by the t<TT epilogue check)
#pragma unroll
    for (int ks = 16; ks < 18; ++ks) {
        U16 ah[4], al[4], bh[4], bl[4];
#pragma unroll
        for (int i = 0; i < 4; i++) {
            size_t co = ((size_t)b * TP + m0 + ar + i * 16 + mrow) * 64 + (ks - 16) * 32 + kq;
            ah[i].u = *(const uint4*)(Chi + co);
            al[i].u = *(const uint4*)(Clo + co);
            bh[i].u = *(const uint4*)(bph[i] + ks * 32);
            bl[i].u = *(const uint4*)(bpl[i] + ks * 32);
        }
#pragma unroll
        for (int i = 0; i < 4; i++) {
#pragma unroll
            for (int j = 0; j < 4; j++)
                acc[i][j] = __builtin_amdgcn_mfma_f32_16x16x32_bf16(ah[i].v, bh[j].v, acc[i][j], 0, 0, 0);
            if (corr[i]) {
#pragma unroll
                for (int j = 0; j < 4; j++) {
                    acc[i][j] = __builtin_amdgcn_mfma_f32_16x16x32_bf16(ah[i].v, bl[j].v, acc[i][j], 0, 0, 0);
                    acc[i][j] = __builtin_amdgcn_mfma_f32_16x16x32_bf16(al[i].v, bh[j].v, acc[i][j], 0, 0, 0);
                }
            }
        }
    }

    gemm_epilogue(acc, dec_a, vvec, energy, b, m0, n0, wm, wn, lane);
}

// ---------- masked softmax over time (replicates energy * (+1 / -1024) mask) ----------
__global__ __launch_bounds__(1024) void k_softmax(const float* __restrict__ energy,
                                                  const int* __restrict__ x_lens,
                                                  float* __restrict__ aw) {
    const int b = blockIdx.x >> 2, h = blockIdx.x & 3;
    const int tid = threadIdx.x;
    __shared__ float sE[TT];
    __shared__ float red[1024];
    const int xlen = x_lens[b];
    float lmax = -3.4e38f;
    for (int t = tid; t < TT; t += 1024) {
        float e = energy[((size_t)b * HH + h) * TP + t];
        float m = (t < xlen) ? e : e * -1024.0f;
        sE[t] = m;
        lmax = fmaxf(lmax, m);
    }
    red[tid] = lmax; __syncthreads();
    for (int s = 512; s > 0; s >>= 1) { if (tid < s) red[tid] = fmaxf(red[tid], red[tid + s]); __syncthreads(); }
    float mx = red[0]; __syncthreads();
    float lsum = 0.f;
    for (int t = tid; t < TT; t += 1024) {
        float ex = __expf(sE[t] - mx);
        sE[t] = ex; lsum += ex;
    }
    red[tid] = lsum; __syncthreads();
    for (int s = 512; s > 0; s >>= 1) { if (tid < s) red[tid] += red[tid + s]; __syncthreads(); }
    float rs = 1.0f / red[0];
    for (int t = tid; t < TT; t += 1024)
        aw[((size_t)b * TT + t) * HH + h] = sE[t] * rs;
}

// ---------- ctx_h[b][h][e] = sum_t aw[b][t][h] * enc[b][t][e] ----------
__global__ __launch_bounds__(256) void k_ctx(const float* __restrict__ enc,
                                             const float* __restrict__ aw,
                                             float* __restrict__ ctx_h) {
    const int chunk = blockIdx.x, b = blockIdx.y;   // 24 x 32
    const int t0 = chunk * 64;
    const int nt = (TT - t0 < 64) ? (TT - t0) : 64;
    __shared__ float sA[64 * 4];
    __shared__ float4 red4[128][4];
    __shared__ int s_nz;
    const int tid = threadIdx.x;
    if (tid == 0) s_nz = 0;
    __syncthreads();
    for (int i = tid; i < nt * 4; i += 256) {
        float w = aw[((size_t)b * TT + t0) * HH + i];
        sA[i] = w;
        if (w != 0.f) s_nz = 1;            // race-benign: all writers store 1
    }
    __syncthreads();
    if (!s_nz) return;
    const int e4 = (tid & 127) * 4;
    const int tg = tid >> 7;               // 0..1
    const float* ep = enc + ((size_t)b * TT + t0) * EE + e4;
    float acc[4][4] = {};                  // [h][e-comp]
#pragma unroll 4
    for (int tt = tg; tt < nt; tt += 2) {
        float4 ev = *reinterpret_cast<const float4*>(ep + (size_t)tt * EE);
        float w0 = sA[tt * 4 + 0], w1 = sA[tt * 4 + 1];
        float w2 = sA[tt * 4 + 2], w3 = sA[tt * 4 + 3];
        acc[0][0] += w0 * ev.x; acc[0][1] += w0 * ev.y; acc[0][2] += w0 * ev.z; acc[0][3] += w0 * ev.w;
        acc[1][0] += w1 * ev.x; acc[1][1] += w1 * ev.y; acc[1][2] += w1 * ev.z; acc[1][3] += w1 * ev.w;
        acc[2][0] += w2 * ev.x; acc[2][1] += w2 * ev.y; acc[2][2] += w2 * ev.z; acc[2][3] += w2 * ev.w;
        acc[3][0] += w3 * ev.x; acc[3][1] += w3 * ev.y; acc[3][2] += w3 * ev.z; acc[3][3] += w3 * ev.w;
    }
    if (tg == 1) {
#pragma unroll
        for (int h = 0; h < 4; ++h)
            red4[tid & 127][h] = make_float4(acc[h][0], acc[h][1], acc[h][2], acc[h][3]);
    }
    __syncthreads();
    if (tg == 0) {
#pragma unroll
        for (int h = 0; h < 4; ++h) {
            float4 o = red4[tid][h];
            float* dst = &ctx_h[((size_t)b * HH + h) * EE + e4];
            atomicAdd(dst + 0, acc[h][0] + o.x);
            atomicAdd(dst + 1, acc[h][1] + o.y);
            atomicAdd(dst + 2, acc[h][2] + o.z);
            atomicAdd(dst + 3, acc[h][3] + o.w);
        }
    }
}

// ---------- ctx = ctx_h @ w_mha + b_mha ----------
__global__ __launch_bounds__(256) void k_mha(const float* __restrict__ ctx_h,
                                             const float* __restrict__ w_mha,
                                             const float* __restrict__ b_mha,
                                             float* __restrict__ out) {
    __shared__ float sred[256];
    const int tid = threadIdx.x;
    const int b  = blockIdx.x >> 2;
    const int eo = ((blockIdx.x & 3) << 7) + (tid & 127);
    const int kg = tid >> 7;                   // 0..1, 1024 k each
    const float* c = ctx_h + (size_t)b * NN + kg * 1024;
    const float* w = w_mha + ((size_t)kg * 1024) * EE + eo;
    float acc = 0.f;
#pragma unroll 8
    for (int k = 0; k < 1024; ++k) acc += c[k] * w[(size_t)k * EE];
    sred[tid] = acc;
    __syncthreads();
    if (tid < 128)
        out[(size_t)b * EE + eo] = b_mha[eo] + sred[tid] + sred[tid + 128];
}

extern "C" void kernel_launch(void* const* d_in, const int* in_sizes, int n_in,
                              void* d_out, int out_size, void* d_ws, size_t ws_size,
                              hipStream_t stream) {
    (void)in_sizes; (void)n_in; (void)out_size;
    const float* enc    = (const float*)d_in[0];
    const int*   xlen   = (const int*)d_in[1];
    const float* dec    = (const float*)d_in[2];
    const float* aw_in  = (const float*)d_in[3];
    const float* w_enc  = (const float*)d_in[4];
    const float* b_enc  = (const float*)d_in[5];
    const float* w_dec  = (const float*)d_in[6];
    const float* w_conv = (const float*)d_in[7];
    const float* convk  = (const float*)d_in[8];
    const float* v      = (const float*)d_in[9];
    const float* w_mha  = (const float*)d_in[10];
    const float* b_mha  = (const float*)d_in[11];
    float* out = (float*)d_out;

    // ws layout (~18.6 MB)
    char* ws = (char*)d_ws;
    unsigned short* Whi = (unsigned short*)ws;                   // 2,359,296 B
    unsigned short* Wlo = (unsigned short*)(ws + 2359296);       // 2,359,296 B
    unsigned short* Chi = (unsigned short*)(ws + 4718592);       // 6,291,456 B
    unsigned short* Clo = (unsigned short*)(ws + 11010048);      // 6,291,456 B
    float* dec_a  = (float*)(ws + 17301504);                     //   262,144 B
    float* energy = (float*)(ws + 17563648);                     //   786,432 B
    float* ctx_h  = (float*)(ws + 18350080);                     //   262,144 B (contiguous after energy)
    (void)ws_size;

    k_prep<<<dim3(PREP_TOTAL), 256, 0, stream>>>(dec, aw_in, w_enc, b_enc,
                                                 w_dec, w_conv, convk,
                                                 Whi, Wlo, Chi, Clo, dec_a, energy);
    k_gemm_v<<<dim3(16, 12, BB), 256, 0, stream>>>(enc, Chi, Whi, dec_a, v, xlen, energy);
    k_gemm_p<<<dim3(16, 12, BB), 256, 0, stream>>>(enc, Chi, Clo, Whi, Wlo, dec_a, v, xlen, energy);
    k_softmax<<<dim3(BB * HH), 1024, 0, stream>>>(energy, xlen, out + 16384);
    k_ctx <<<dim3(24, BB), 256, 0, stream>>>(enc, out + 16384, ctx_h);
    k_mha <<<dim3(128), 256, 0, stream>>>(ctx_h, w_mha, b_mha, out);
}